// Round 9
// baseline (4604.467 us; speedup 1.0000x reference)
//
#include <hip/hip_runtime.h>
#include <stdint.h>

// ---------------------------------------------------------------------------
// StageNet forward on MI355X — ROUND 9 (first perf round; R8 passed @4533us).
// R8 profile: monolithic k_scan = 3627us, latency-bound (Occ 12%, VALU 11%,
// 1 block/CU re-streams 2.4MB Wr per step). Fix: per-step kernel k_step
// (grid 25 g-tiles x 8 b-tiles, gates(t-1) fused + xout_t GEMM, parity
// buffers; round-4-proven semantics) + k_final. hbuf/out fp32.
// Pipeline: detect -> canonicalize -> PH1 MFMA gather-GEMM XKb(bf16) ->
// 50x k_step -> k_final (fp32 out).
// ---------------------------------------------------------------------------

typedef unsigned short u16;
typedef short bf16x8 __attribute__((ext_vector_type(8)));
typedef float f32x4 __attribute__((ext_vector_type(4)));

__device__ __forceinline__ float bf2f(u16 u) {
  union { unsigned int i; float f; } v;
  v.i = ((unsigned int)u) << 16;
  return v.f;
}
__device__ __forceinline__ u16 f2bf(float f) {
  union { float f; unsigned int i; } v;
  v.f = f;
  unsigned int r = (v.i + 0x7fffu + ((v.i >> 16) & 1u)) >> 16;
  return (u16)r;
}
__device__ __forceinline__ float ldf(const void* p, size_t i, int isbf) {
  return isbf ? bf2f(((const u16*)p)[i]) : ((const float*)p)[i];
}
__device__ __forceinline__ float sigf(float x) { return 1.f / (1.f + __expf(-x)); }
__device__ __forceinline__ float tanhf_(float x) {
  float cx = fminf(fmaxf(x, -15.f), 15.f);
  float e = __expf(2.f * cx);
  return (e - 1.f) / (e + 1.f);
}
__device__ __forceinline__ float dot8_bf(const u16* w, const float* lp) {
  uint4 wv = *(const uint4*)w;
  union { unsigned int u; float f; } a0, a1;
  float s;
  a0.u = wv.x << 16; a1.u = wv.x & 0xffff0000u;
  s = lp[0] * a0.f + lp[1] * a1.f;
  a0.u = wv.y << 16; a1.u = wv.y & 0xffff0000u;
  s += lp[2] * a0.f + lp[3] * a1.f;
  a0.u = wv.z << 16; a1.u = wv.z & 0xffff0000u;
  s += lp[4] * a0.f + lp[5] * a1.f;
  a0.u = wv.w << 16; a1.u = wv.w & 0xffff0000u;
  s += lp[6] * a0.f + lp[7] * a1.f;
  return s;
}

// ------------------------- dtype detection (safety) ------------------------
__global__ void k_detect(const unsigned int* __restrict__ emb_raw,
                         int* __restrict__ flag) {
  if (blockIdx.x == 0 && threadIdx.x == 0) {
    int cnt = 0;
    for (int i = 64; i < 128; ++i) {
      unsigned int u = emb_raw[i];
      unsigned int lo = u & 0xffffu;
      unsigned int ex = (lo >> 7) & 0xffu;
      if (lo != 0 && ex >= 100 && ex <= 126) ++cnt;
    }
    *flag = (cnt >= 32) ? 1 : 0;
  }
}

// ------------------------- canonicalization --------------------------------
__global__ void k_cvt_emb(const void* __restrict__ src, u16* __restrict__ dst,
                          const int* __restrict__ flagp) {
  int isbf = *flagp;
  int n = 10001 * 128;
  int i = blockIdx.x * blockDim.x + threadIdx.x;
  int stride = gridDim.x * blockDim.x;
  for (; i < n; i += stride)
    dst[i] = isbf ? ((const u16*)src)[i] : f2bf(((const float*)src)[i]);
}

__global__ void k_repack_wk(const void* __restrict__ wk, u16* __restrict__ wkp,
                            const int* __restrict__ flagp) {
  int isbf = *flagp;
  size_t i = (size_t)blockIdx.x * blockDim.x + threadIdx.x;
  size_t total = (size_t)1664 * 8192;
  size_t stride = (size_t)gridDim.x * blockDim.x;
  for (; i < total; i += stride) {
    size_t g = i >> 13, k = i & 8191;
    wkp[i] = (g < 1552) ? f2bf(ldf(wk, g * 8193 + k, isbf)) : (u16)0;
  }
}

__global__ void k_prep_wr(const void* __restrict__ wr, const void* __restrict__ wk,
                          const void* __restrict__ bk, const void* __restrict__ br,
                          float* __restrict__ wrp, float* __restrict__ biasC,
                          float* __restrict__ wlC, const int* __restrict__ flagp) {
  int isbf = *flagp;
  int i0 = blockIdx.x * blockDim.x + threadIdx.x;
  int stride = gridDim.x * blockDim.x;
  for (int j = i0; j < 1552 * 384; j += stride) {
    int g = j / 384, k = j - g * 384;
    wrp[j] = ldf(wr, g * 385 + k, isbf);
  }
  for (int g = i0; g < 1552; g += stride) {
    biasC[g] = ldf(bk, g, isbf) + ldf(br, g, isbf);
    wlC[g] = ldf(wk, (size_t)g * 8193 + 8192, isbf) + ldf(wr, g * 385 + 384, isbf);
  }
}

__global__ void k_repack_wc(const void* __restrict__ wc, u16* __restrict__ wcp,
                            const int* __restrict__ flagp) {
  int isbf = *flagp;
  int i0 = blockIdx.x * blockDim.x + threadIdx.x;
  int stride = gridDim.x * blockDim.x;
  for (int j = i0; j < 384 * 3840; j += stride) {
    int o = j / 3840;
    int r = j - o * 3840;
    int k = r / 384;
    int h = r - k * 384;
    wcp[j] = f2bf(ldf(wc, (o * 384 + h) * 10 + k, isbf));  // [o][h][k]->[o][k][h]
  }
}

// canonical fp32: [vt 12800][Ws 24576][bs 64][Wrs 24576][brs 384][bc 384]
//                 [Wo 49152][bo 128]  (total 112064 floats)
__global__ void k_cvt_smalls(const void* vt, const void* Ws, const void* bs,
                             const void* Wrs, const void* brs, const void* bc,
                             const void* Wo, const void* bo,
                             float* __restrict__ dst, const int* __restrict__ flagp) {
  int isbf = *flagp;
  int i = blockIdx.x * blockDim.x + threadIdx.x;
  int stride = gridDim.x * blockDim.x;
  for (; i < 112064; i += stride) {
    float v;
    if (i < 12800) v = ldf(vt, i, isbf);
    else if (i < 37376) v = ldf(Ws, i - 12800, isbf);
    else if (i < 37440) v = ldf(bs, i - 37376, isbf);
    else if (i < 62016) v = ldf(Wrs, i - 37440, isbf);
    else if (i < 62400) v = ldf(brs, i - 62016, isbf);
    else if (i < 62784) v = ldf(bc, i - 62400, isbf);
    else if (i < 111936) v = ldf(Wo, i - 62784, isbf);
    else v = ldf(bo, i - 111936, isbf);
    dst[i] = v;
  }
}

__global__ void k_zero(float* __restrict__ p, int n) {
  int i = blockIdx.x * blockDim.x + threadIdx.x;
  int stride = gridDim.x * blockDim.x;
  for (; i < n; i += stride) p[i] = 0.f;
}

// ------------------------- PH1: gathered GEMM -> XK (bf16), MFMA -----------
// grid (13 g-tiles, 100 m-tiles), 256 threads. Tile 128x128, BK=64 bf16.
__global__ __launch_bounds__(256) void k_gemm_xk(
    const int* __restrict__ node_ids, const u16* __restrict__ embB,
    const u16* __restrict__ wkp, const float* __restrict__ vtF,
    const float* __restrict__ biasC, const float* __restrict__ wlC,
    u16* __restrict__ xkb) {
  __shared__ alignas(16) u16 As[128 * 64];
  __shared__ alignas(16) u16 Bs[128 * 64];
  int tid = threadIdx.x;
  int m0 = blockIdx.y * 128;
  int g0 = blockIdx.x * 128;
  int lane = tid & 63, w = tid >> 6;
  int wy = w >> 1, wx = w & 1;
  f32x4 acc[4][4];
#pragma unroll
  for (int i = 0; i < 4; ++i)
#pragma unroll
    for (int j = 0; j < 4; ++j) acc[i][j] = (f32x4){0.f, 0.f, 0.f, 0.f};

  int r = tid >> 1, halfsel = tid & 1;
  int l15 = lane & 15, lq = lane >> 4;

  for (int kt = 0; kt < 128; ++kt) {
    __syncthreads();
    {
      int id = node_ids[(size_t)(m0 + r) * 64 + (kt >> 1)];
      const uint4* src =
          (const uint4*)(embB + (size_t)id * 128 + (kt & 1) * 64 + halfsel * 32);
      uint4* dst = (uint4*)(As + r * 64 + halfsel * 32);
      uint4 a0 = src[0], a1 = src[1], a2 = src[2], a3 = src[3];
      dst[0] = a0; dst[1] = a1; dst[2] = a2; dst[3] = a3;
    }
    {
      const uint4* src = (const uint4*)(wkp + (size_t)(g0 + r) * 8192 +
                                        (size_t)kt * 64 + halfsel * 32);
      uint4* dst = (uint4*)(Bs + r * 64 + halfsel * 32);
      uint4 b0 = src[0], b1 = src[1], b2 = src[2], b3 = src[3];
      dst[0] = b0; dst[1] = b1; dst[2] = b2; dst[3] = b3;
    }
    __syncthreads();
    const u16* Ab = As + (wy * 64 + l15) * 64 + lq * 8;
    const u16* Bb = Bs + (wx * 64 + l15) * 64 + lq * 8;
#pragma unroll
    for (int ks = 0; ks < 2; ++ks) {
      bf16x8 av[4], bv[4];
#pragma unroll
      for (int i = 0; i < 4; ++i) av[i] = *(const bf16x8*)(Ab + ks * 32 + i * 1024);
#pragma unroll
      for (int j = 0; j < 4; ++j) bv[j] = *(const bf16x8*)(Bb + ks * 32 + j * 1024);
#pragma unroll
      for (int i = 0; i < 4; ++i)
#pragma unroll
        for (int j = 0; j < 4; ++j)
          acc[i][j] =
              __builtin_amdgcn_mfma_f32_16x16x32_bf16(av[i], bv[j], acc[i][j], 0, 0, 0);
    }
  }
  float vt[4][4];
#pragma unroll
  for (int i = 0; i < 4; ++i)
#pragma unroll
    for (int p = 0; p < 4; ++p)
      vt[i][p] = vtF[m0 + wy * 64 + i * 16 + lq * 4 + p];
#pragma unroll
  for (int j = 0; j < 4; ++j) {
    int gcol = g0 + wx * 64 + j * 16 + l15;
    if (gcol < 1552) {
      float bC = biasC[gcol], wC = wlC[gcol];
#pragma unroll
      for (int i = 0; i < 4; ++i)
#pragma unroll
        for (int p = 0; p < 4; ++p) {
          int grow = m0 + wy * 64 + i * 16 + lq * 4 + p;
          xkb[(size_t)grow * 1552 + gcol] = f2bf(acc[i][j][p] + bC + vt[i][p] * wC);
        }
    }
  }
}

// ------------------------- PH2: per-step scan kernel -----------------------
// launch t: gates of step t-1 (redundant per g-tile) + xout_t = XK_t + h@Wr^T.
// grid (25 g-tiles of 64, 8 b-tiles of 32), 256 threads.
__global__ __launch_bounds__(256) void k_step(
    const u16* __restrict__ xkb, const float* __restrict__ wrp,
    const float* __restrict__ xoutA, float* __restrict__ xoutB,
    const float* __restrict__ cIn, float* __restrict__ cOut,
    float* __restrict__ hbuf, float* __restrict__ dbuf, int t) {
  __shared__ alignas(16) float HsT[384][34];  // h^T [k][b_local], pad 34
  __shared__ alignas(16) float fmS[32][8], imS[32][8];
  int tid = threadIdx.x;
  int g0 = blockIdx.x * 64, b0 = blockIdx.y * 32;

  if (t > 0) {
    if (tid < 32) {
      int b = b0 + tid;
      const float* xr = xoutA + (size_t)b * 1552;
      float z[8], e[8], m, s, inv, run, fsum;
      m = -1e30f;
      for (int j = 0; j < 8; ++j) { z[j] = xr[j]; m = fmaxf(m, z[j]); }
      s = 0.f;
      for (int j = 0; j < 8; ++j) { e[j] = __expf(z[j] - m); s += e[j]; }
      inv = 1.f / s; run = 0.f; fsum = 0.f;
      for (int j = 0; j < 8; ++j) { run += e[j] * inv; fmS[tid][j] = run; fsum += run; }
      dbuf[(size_t)(t - 1) * 256 + b] = 1.f - fsum * 0.125f;
      m = -1e30f;
      for (int j = 0; j < 8; ++j) { z[j] = xr[8 + j]; m = fmaxf(m, z[j]); }
      s = 0.f;
      for (int j = 0; j < 8; ++j) { e[j] = __expf(z[j] - m); s += e[j]; }
      inv = 1.f / s; run = 0.f;
      for (int j = 7; j >= 0; --j) { run += e[j] * inv; imS[tid][j] = run; }
    }
    __syncthreads();
    for (int rep = 0; rep < 48; ++rep) {
      int eidx = rep * 256 + tid;
      int bl = eidx / 384;
      int h = eidx - bl * 384;
      int l = h / 48;
      int b = b0 + bl;
      const float* xg = xoutA + (size_t)b * 1552 + 16;
      float fg = sigf(xg[h]);
      float ig = sigf(xg[h + 384]);
      float og = sigf(xg[h + 768]);
      float ci = tanhf_(xg[h + 1152]);
      float cl = cIn[b * 384 + h];
      float fm = fmS[bl][l], im = imS[bl][l];
      float ov = fm * im;
      float cn = ov * (fg * cl + ig * ci) + (fm - ov) * cl + (im - ov) * ci;
      float hn = og * tanhf_(cn);
      cOut[b * 384 + h] = cn;
      hbuf[((size_t)(t - 1) * 256 + b) * 384 + h] = hn;
      HsT[h][bl] = hn;
    }
  } else {
    for (int i = tid; i < 384 * 34; i += 256) ((float*)HsT)[i] = 0.f;
  }
  __syncthreads();

  // xout_t = XK[:,t,:] + h_{t-1} @ Wr^T
  int tx = tid & 15, ty = tid >> 4;
  float acc[2][4] = {{0.f, 0.f, 0.f, 0.f}, {0.f, 0.f, 0.f, 0.f}};
  if (t > 0) {
    const float* wp[4];
#pragma unroll
    for (int jj = 0; jj < 4; ++jj) {
      int g = g0 + tx * 4 + jj;
      wp[jj] = wrp + (size_t)(g < 1552 ? g : 1551) * 384;
    }
    for (int c0 = 0; c0 < 384; c0 += 64) {
#pragma unroll
      for (int k4 = 0; k4 < 16; ++k4) {
        int kk = c0 + k4 * 4;
        f32x4 wv[4];
#pragma unroll
        for (int jj = 0; jj < 4; ++jj) wv[jj] = *(const f32x4*)(wp[jj] + kk);
#pragma unroll
        for (int q = 0; q < 4; ++q) {
          float2 hq = *(const float2*)&HsT[kk + q][ty * 2];
#pragma unroll
          for (int jj = 0; jj < 4; ++jj) {
            acc[0][jj] += hq.x * wv[jj][q];
            acc[1][jj] += hq.y * wv[jj][q];
          }
        }
      }
    }
  }
#pragma unroll
  for (int ii = 0; ii < 2; ++ii)
#pragma unroll
    for (int jj = 0; jj < 4; ++jj) {
      int g = g0 + tx * 4 + jj;
      if (g < 1552) {
        int b = b0 + ty * 2 + ii;
        xoutB[(size_t)b * 1552 + g] =
            acc[ii][jj] + bf2f(xkb[((size_t)b * 50 + t) * 1552 + g]);
      }
    }
}

// ------------------------- PH3: final (gates49 + theme/conv/out) -----------
__global__ __launch_bounds__(384) void k_final(
    const float* __restrict__ xout49, const float* __restrict__ c48,
    const float* __restrict__ hbuf, const float* __restrict__ dbuf,
    const unsigned char* __restrict__ am, const float* __restrict__ smalls,
    const u16* __restrict__ wcp, float* __restrict__ out) {
  const float* WsF = smalls + 12800;
  const float* bsF = smalls + 37376;
  const float* WrsF = smalls + 37440;
  const float* brsF = smalls + 62016;
  const float* bcF = smalls + 62400;
  const float* WoF = smalls + 62784;
  const float* boF = smalls + 111936;
  __shared__ alignas(16) float Hl[384];
  __shared__ alignas(16) float lh2[10][384];
  __shared__ alignas(16) float ti[384];
  __shared__ alignas(16) float us[64];
  __shared__ alignas(16) float rnnS[384];
  __shared__ alignas(16) float hlastS[384];
  __shared__ float fm8[8], im8[8], ldS[10];
  __shared__ float d49S;
  __shared__ int npad[50];
  __shared__ int lastS;
  int tid = threadIdx.x;
  int b = blockIdx.x;

  if (tid < 50) {
    const unsigned char* mr = am + ((size_t)b * 50 + tid) * 64;
    int all1 = 1;
    for (int q = 0; q < 64; ++q) all1 &= (mr[q] != 0);
    npad[tid] = all1 ? 0 : 1;
  }
  if (tid == 0) {
    const float* xr = xout49 + (size_t)b * 1552;
    float z[8], e[8], m, s, inv, run, fsum;
    m = -1e30f;
    for (int j = 0; j < 8; ++j) { z[j] = xr[j]; m = fmaxf(m, z[j]); }
    s = 0.f;
    for (int j = 0; j < 8; ++j) { e[j] = __expf(z[j] - m); s += e[j]; }
    inv = 1.f / s; run = 0.f; fsum = 0.f;
    for (int j = 0; j < 8; ++j) { run += e[j] * inv; fm8[j] = run; fsum += run; }
    d49S = 1.f - fsum * 0.125f;
    m = -1e30f;
    for (int j = 0; j < 8; ++j) { z[j] = xr[8 + j]; m = fmaxf(m, z[j]); }
    s = 0.f;
    for (int j = 0; j < 8; ++j) { e[j] = __expf(z[j] - m); s += e[j]; }
    inv = 1.f / s; run = 0.f;
    for (int j = 7; j >= 0; --j) { run += e[j] * inv; im8[j] = run; }
  }
  __syncthreads();
  {  // gates for step 49 -> h49
    int h = tid;
    const float* xg = xout49 + (size_t)b * 1552 + 16;
    int l = h / 48;
    float fg = sigf(xg[h]);
    float ig = sigf(xg[h + 384]);
    float og = sigf(xg[h + 768]);
    float ci = tanhf_(xg[h + 1152]);
    float cl = c48[b * 384 + h];
    float fm = fm8[l], im = im8[l];
    float ov = fm * im;
    float cn = ov * (fg * cl + ig * ci) + (fm - ov) * cl + (im - ov) * ci;
    Hl[h] = og * tanhf_(cn);
  }
  if (tid == 0) {
    int c = 0;
    for (int v = 0; v < 50; ++v) c += npad[v];
    int lv = c - 1;
    lastS = lv < 0 ? 0 : lv;
  }
  __syncthreads();
  if (tid == 0) {  // window cumsum + softmax -> local_dis
    float cum = 0.f, cv[10];
    for (int k = 0; k < 10; ++k) {
      int s = lastS - 9 + k;
      float dk = 0.f;
      if (s >= 0) dk = (s == 49) ? d49S : dbuf[(size_t)s * 256 + b];
      cum += dk;
      cv[k] = cum;
    }
    float m = cv[0];
    for (int k = 1; k < 10; ++k) m = fmaxf(m, cv[k]);
    float ssum = 0.f, ee[10];
    for (int k = 0; k < 10; ++k) { ee[k] = __expf(cv[k] - m); ssum += ee[k]; }
    float inv = 1.f / ssum;
    for (int k = 0; k < 10; ++k) ldS[k] = ee[k] * inv;
  }
  __syncthreads();
  {  // local_h, theme input, h_last
    int h = tid;
    float ssum = 0.f;
    for (int k = 0; k < 10; ++k) {
      int s = lastS - 9 + k;
      float hv = 0.f;
      if (s >= 0)
        hv = (s == 49) ? Hl[h] : hbuf[((size_t)s * 256 + b) * 384 + h];
      float v = hv * ldS[k];
      lh2[k][h] = v;
      ssum += v;
    }
    ti[h] = ssum * 0.1f;
    hlastS[h] = (lastS == 49) ? Hl[h] : hbuf[((size_t)lastS * 256 + b) * 384 + h];
  }
  __syncthreads();
  if (tid < 64) {  // u = relu(ti @ Ws^T + bs)
    float a = bsF[tid];
    const float* wr = WsF + (size_t)tid * 384;
    for (int h = 0; h < 384; ++h) a += wr[h] * ti[h];
    us[tid] = fmaxf(a, 0.f);
  }
  __syncthreads();
  {  // theme = sigmoid(u @ Wrs^T + brs); conv; rnn = theme*conv + h_last
    int o = tid;
    float th = brsF[o];
    const float* wr = WrsF + (size_t)o * 64;
    for (int k = 0; k < 64; ++k) th += wr[k] * us[k];
    th = sigf(th);
    float cacc = bcF[o];
    for (int k = 0; k < 10; ++k) {
      const u16* wrow = wcp + ((size_t)o * 10 + k) * 384;
      const float* lrow = lh2[k];
      for (int h8 = 0; h8 < 48; ++h8) cacc += dot8_bf(wrow + h8 * 8, lrow + h8 * 8);
    }
    rnnS[o] = th * cacc + hlastS[o];
  }
  __syncthreads();
  if (tid < 128) {  // out = rnn @ Wo^T + bo, FP32 OUT
    float a = boF[tid];
    const float* wr = WoF + (size_t)tid * 384;
    for (int h = 0; h < 384; ++h) a += wr[h] * rnnS[h];
    out[(size_t)b * 128 + tid] = a;
  }
}

// ------------------------- launch ------------------------------------------
extern "C" void kernel_launch(void* const* d_in, const int* in_sizes, int n_in,
                              void* d_out, int out_size, void* d_ws, size_t ws_size,
                              hipStream_t stream) {
  const int* node_ids = (const int*)d_in[0];
  const void* vtR = d_in[3];
  const unsigned char* am = (const unsigned char*)d_in[5];
  const void* embR = d_in[6];
  const void* WkR = d_in[7];
  const void* bkR = d_in[8];
  const void* WrR = d_in[9];
  const void* brR = d_in[10];
  const void* WsR = d_in[11];
  const void* bsR = d_in[12];
  const void* WrsR = d_in[13];
  const void* brsR = d_in[14];
  const void* WcR = d_in[15];
  const void* bcR = d_in[16];
  const void* WoR = d_in[17];
  const void* boR = d_in[18];
  (void)in_sizes; (void)n_in; (void)out_size; (void)ws_size;

  char* ws = (char*)d_ws;
  size_t off = 0;
  auto alloc = [&](size_t bytes) {
    void* p = ws + off;
    off = (off + bytes + 255) & ~(size_t)255;
    return p;
  };
  int* flagp = (int*)alloc(4);
  u16* embB = (u16*)alloc((size_t)10001 * 128 * 2);      // 2.56MB
  u16* WkP = (u16*)alloc((size_t)1664 * 8192 * 2);       // 27.3MB
  float* WrP = (float*)alloc((size_t)1552 * 384 * 4);    // 2.4MB
  float* biasC = (float*)alloc(1552 * 4);
  float* wlC = (float*)alloc(1552 * 4);
  float* smalls = (float*)alloc((size_t)112064 * 4);
  u16* XKb = (u16*)alloc((size_t)12800 * 1552 * 2);      // 39.7MB
  u16* WcP = (u16*)alloc((size_t)384 * 3840 * 2);        // 2.9MB
  float* xout = (float*)alloc((size_t)2 * 256 * 1552 * 4);  // 3.2MB
  float* Cbuf = (float*)alloc((size_t)2 * 256 * 384 * 4);   // 0.8MB
  float* Hbuf = (float*)alloc((size_t)50 * 256 * 384 * 4);  // 19.7MB
  float* Dbuf = (float*)alloc((size_t)50 * 256 * 4);

  k_detect<<<dim3(1), dim3(64), 0, stream>>>((const unsigned int*)embR, flagp);
  k_cvt_emb<<<dim3(1024), dim3(256), 0, stream>>>(embR, embB, flagp);
  k_repack_wk<<<dim3(2048), dim3(256), 0, stream>>>(WkR, WkP, flagp);
  k_prep_wr<<<dim3(512), dim3(256), 0, stream>>>(WrR, WkR, bkR, brR, WrP, biasC,
                                                 wlC, flagp);
  k_repack_wc<<<dim3(512), dim3(256), 0, stream>>>(WcR, WcP, flagp);
  k_cvt_smalls<<<dim3(128), dim3(256), 0, stream>>>(vtR, WsR, bsR, WrsR, brsR,
                                                    bcR, WoR, boR, smalls, flagp);
  k_zero<<<dim3(96), dim3(256), 0, stream>>>(Cbuf, 256 * 384);  // c_{-1}=0

  k_gemm_xk<<<dim3(13, 100), dim3(256), 0, stream>>>(node_ids, embB, WkP, smalls,
                                                     biasC, wlC, XKb);

  for (int t = 0; t < 50; ++t) {
    const float* xA = xout + (size_t)((t + 1) & 1) * (256 * 1552);
    float* xB = xout + (size_t)(t & 1) * (256 * 1552);
    const float* cI = Cbuf + (size_t)((t + 1) & 1) * (256 * 384);
    float* cO = Cbuf + (size_t)(t & 1) * (256 * 384);
    k_step<<<dim3(25, 8), dim3(256), 0, stream>>>(XKb, WrP, xA, xB, cI, cO, Hbuf,
                                                  Dbuf, t);
  }

  k_final<<<dim3(256), dim3(384), 0, stream>>>(
      xout + (size_t)1 * (256 * 1552), Cbuf + (size_t)1 * (256 * 384), Hbuf, Dbuf,
      am, smalls, WcP, (float*)d_out);
}

// Round 10
// 2277.800 us; speedup vs baseline: 2.0215x; 2.0215x over previous
//
#include <hip/hip_runtime.h>
#include <stdint.h>

// ---------------------------------------------------------------------------
// StageNet forward on MI355X — ROUND 10.
// R9: k_step 71us/step (uncoalesced Wr rows + 1 wave/SIMD), k_gemm_xk 926us
// with 2.56e8 LDS bank conflicts (32-way staging ds_write pattern).
// This round:
//  * k_step v3: WrT[384][1600] transposed weights (lane g = fast axis,
//    coalesced), 64g x 8b tiles, grid (25,32)=800 blocks (~3/CU TLP).
//  * k_gemm_xk v2: global_load_lds width-16 staging for A (gather) and B —
//    no ds_writes, no bank conflicts, no VGPR round trip.
// Pipeline: detect -> canonicalize -> PH1 MFMA gather-GEMM XKb(bf16) ->
// 50x k_step -> k_final (fp32 out).
// ---------------------------------------------------------------------------

typedef unsigned short u16;
typedef short bf16x8 __attribute__((ext_vector_type(8)));
typedef float f32x4 __attribute__((ext_vector_type(4)));

#define GLL(gp, lp)                                                            \
  __builtin_amdgcn_global_load_lds(                                            \
      (const __attribute__((address_space(1))) unsigned int*)(gp),             \
      (__attribute__((address_space(3))) unsigned int*)(lp), 16, 0, 0)

__device__ __forceinline__ float bf2f(u16 u) {
  union { unsigned int i; float f; } v;
  v.i = ((unsigned int)u) << 16;
  return v.f;
}
__device__ __forceinline__ u16 f2bf(float f) {
  union { float f; unsigned int i; } v;
  v.f = f;
  unsigned int r = (v.i + 0x7fffu + ((v.i >> 16) & 1u)) >> 16;
  return (u16)r;
}
__device__ __forceinline__ float ldf(const void* p, size_t i, int isbf) {
  return isbf ? bf2f(((const u16*)p)[i]) : ((const float*)p)[i];
}
__device__ __forceinline__ float sigf(float x) { return 1.f / (1.f + __expf(-x)); }
__device__ __forceinline__ float tanhf_(float x) {
  float cx = fminf(fmaxf(x, -15.f), 15.f);
  float e = __expf(2.f * cx);
  return (e - 1.f) / (e + 1.f);
}
__device__ __forceinline__ float dot8_bf(const u16* w, const float* lp) {
  uint4 wv = *(const uint4*)w;
  union { unsigned int u; float f; } a0, a1;
  float s;
  a0.u = wv.x << 16; a1.u = wv.x & 0xffff0000u;
  s = lp[0] * a0.f + lp[1] * a1.f;
  a0.u = wv.y << 16; a1.u = wv.y & 0xffff0000u;
  s += lp[2] * a0.f + lp[3] * a1.f;
  a0.u = wv.z << 16; a1.u = wv.z & 0xffff0000u;
  s += lp[4] * a0.f + lp[5] * a1.f;
  a0.u = wv.w << 16; a1.u = wv.w & 0xffff0000u;
  s += lp[6] * a0.f + lp[7] * a1.f;
  return s;
}

// ------------------------- dtype detection (safety) ------------------------
__global__ void k_detect(const unsigned int* __restrict__ emb_raw,
                         int* __restrict__ flag) {
  if (blockIdx.x == 0 && threadIdx.x == 0) {
    int cnt = 0;
    for (int i = 64; i < 128; ++i) {
      unsigned int u = emb_raw[i];
      unsigned int lo = u & 0xffffu;
      unsigned int ex = (lo >> 7) & 0xffu;
      if (lo != 0 && ex >= 100 && ex <= 126) ++cnt;
    }
    *flag = (cnt >= 32) ? 1 : 0;
  }
}

// ------------------------- canonicalization --------------------------------
__global__ void k_cvt_emb(const void* __restrict__ src, u16* __restrict__ dst,
                          const int* __restrict__ flagp) {
  int isbf = *flagp;
  int n = 10001 * 128;
  int i = blockIdx.x * blockDim.x + threadIdx.x;
  int stride = gridDim.x * blockDim.x;
  for (; i < n; i += stride)
    dst[i] = isbf ? ((const u16*)src)[i] : f2bf(((const float*)src)[i]);
}

__global__ void k_repack_wk(const void* __restrict__ wk, u16* __restrict__ wkp,
                            const int* __restrict__ flagp) {
  int isbf = *flagp;
  size_t i = (size_t)blockIdx.x * blockDim.x + threadIdx.x;
  size_t total = (size_t)1664 * 8192;
  size_t stride = (size_t)gridDim.x * blockDim.x;
  for (; i < total; i += stride) {
    size_t g = i >> 13, k = i & 8191;
    wkp[i] = (g < 1552) ? f2bf(ldf(wk, g * 8193 + k, isbf)) : (u16)0;
  }
}

// WrT[k][g] fp32, g padded to 1600 with zeros; + biasC, wlC
__global__ void k_prep_wr(const void* __restrict__ wr, const void* __restrict__ wk,
                          const void* __restrict__ bk, const void* __restrict__ br,
                          float* __restrict__ wrT, float* __restrict__ biasC,
                          float* __restrict__ wlC, const int* __restrict__ flagp) {
  int isbf = *flagp;
  int i0 = blockIdx.x * blockDim.x + threadIdx.x;
  int stride = gridDim.x * blockDim.x;
  for (int j = i0; j < 384 * 1600; j += stride) {
    int k = j / 1600, g = j - k * 1600;
    wrT[j] = (g < 1552) ? ldf(wr, (size_t)g * 385 + k, isbf) : 0.f;
  }
  for (int g = i0; g < 1552; g += stride) {
    biasC[g] = ldf(bk, g, isbf) + ldf(br, g, isbf);
    wlC[g] = ldf(wk, (size_t)g * 8193 + 8192, isbf) + ldf(wr, g * 385 + 384, isbf);
  }
}

__global__ void k_repack_wc(const void* __restrict__ wc, u16* __restrict__ wcp,
                            const int* __restrict__ flagp) {
  int isbf = *flagp;
  int i0 = blockIdx.x * blockDim.x + threadIdx.x;
  int stride = gridDim.x * blockDim.x;
  for (int j = i0; j < 384 * 3840; j += stride) {
    int o = j / 3840;
    int r = j - o * 3840;
    int k = r / 384;
    int h = r - k * 384;
    wcp[j] = f2bf(ldf(wc, (o * 384 + h) * 10 + k, isbf));  // [o][h][k]->[o][k][h]
  }
}

// canonical fp32: [vt 12800][Ws 24576][bs 64][Wrs 24576][brs 384][bc 384]
//                 [Wo 49152][bo 128]  (total 112064 floats)
__global__ void k_cvt_smalls(const void* vt, const void* Ws, const void* bs,
                             const void* Wrs, const void* brs, const void* bc,
                             const void* Wo, const void* bo,
                             float* __restrict__ dst, const int* __restrict__ flagp) {
  int isbf = *flagp;
  int i = blockIdx.x * blockDim.x + threadIdx.x;
  int stride = gridDim.x * blockDim.x;
  for (; i < 112064; i += stride) {
    float v;
    if (i < 12800) v = ldf(vt, i, isbf);
    else if (i < 37376) v = ldf(Ws, i - 12800, isbf);
    else if (i < 37440) v = ldf(bs, i - 37376, isbf);
    else if (i < 62016) v = ldf(Wrs, i - 37440, isbf);
    else if (i < 62400) v = ldf(brs, i - 62016, isbf);
    else if (i < 62784) v = ldf(bc, i - 62400, isbf);
    else if (i < 111936) v = ldf(Wo, i - 62784, isbf);
    else v = ldf(bo, i - 111936, isbf);
    dst[i] = v;
  }
}

__global__ void k_zero(float* __restrict__ p, int n) {
  int i = blockIdx.x * blockDim.x + threadIdx.x;
  int stride = gridDim.x * blockDim.x;
  for (; i < n; i += stride) p[i] = 0.f;
}

// ------------------------- PH1: gathered GEMM -> XK (bf16), MFMA + GLL -----
// grid (13 g-tiles, 100 m-tiles), 256 threads. Tile 128x128, BK=64 bf16.
// Staging via global_load_lds width=16: wave w stages chunks w*4..w*4+3,
// chunk = 8 rows x 128B = 1KB contiguous LDS, per-lane gather address.
__global__ __launch_bounds__(256) void k_gemm_xk(
    const int* __restrict__ node_ids, const u16* __restrict__ embB,
    const u16* __restrict__ wkp, const float* __restrict__ vtF,
    const float* __restrict__ biasC, const float* __restrict__ wlC,
    u16* __restrict__ xkb) {
  __shared__ alignas(16) u16 As[128 * 64];
  __shared__ alignas(16) u16 Bs[128 * 64];
  int tid = threadIdx.x;
  int m0 = blockIdx.y * 128;
  int g0 = blockIdx.x * 128;
  int lane = tid & 63, w = tid >> 6;
  int wy = w >> 1, wx = w & 1;
  f32x4 acc[4][4];
#pragma unroll
  for (int i = 0; i < 4; ++i)
#pragma unroll
    for (int j = 0; j < 4; ++j) acc[i][j] = (f32x4){0.f, 0.f, 0.f, 0.f};

  int l15 = lane & 15, lq = lane >> 4;
  int lr = lane >> 3, lc = lane & 7;  // row-in-chunk, 16B-chunk-in-row

  for (int kt = 0; kt < 128; ++kt) {
    __syncthreads();
    // ---- stage A (gathered embed rows) via global_load_lds
#pragma unroll
    for (int c = 0; c < 4; ++c) {
      int chunk = w * 4 + c;
      int r = chunk * 8 + lr;
      int id = node_ids[(size_t)(m0 + r) * 64 + (kt >> 1)];
      const u16* gp = embB + (size_t)id * 128 + (kt & 1) * 64 + lc * 8;
      u16* lp = As + chunk * 512 + lane * 8;
      GLL(gp, lp);
    }
    // ---- stage B (Wk tile) via global_load_lds
#pragma unroll
    for (int c = 0; c < 4; ++c) {
      int chunk = w * 4 + c;
      int r = chunk * 8 + lr;
      const u16* gp = wkp + (size_t)(g0 + r) * 8192 + (size_t)kt * 64 + lc * 8;
      u16* lp = Bs + chunk * 512 + lane * 8;
      GLL(gp, lp);
    }
    __syncthreads();
    const u16* Ab = As + (wy * 64 + l15) * 64 + lq * 8;
    const u16* Bb = Bs + (wx * 64 + l15) * 64 + lq * 8;
#pragma unroll
    for (int ks = 0; ks < 2; ++ks) {
      bf16x8 av[4], bv[4];
#pragma unroll
      for (int i = 0; i < 4; ++i) av[i] = *(const bf16x8*)(Ab + ks * 32 + i * 1024);
#pragma unroll
      for (int j = 0; j < 4; ++j) bv[j] = *(const bf16x8*)(Bb + ks * 32 + j * 1024);
#pragma unroll
      for (int i = 0; i < 4; ++i)
#pragma unroll
        for (int j = 0; j < 4; ++j)
          acc[i][j] =
              __builtin_amdgcn_mfma_f32_16x16x32_bf16(av[i], bv[j], acc[i][j], 0, 0, 0);
    }
  }
  float vt[4][4];
#pragma unroll
  for (int i = 0; i < 4; ++i)
#pragma unroll
    for (int p = 0; p < 4; ++p)
      vt[i][p] = vtF[m0 + wy * 64 + i * 16 + lq * 4 + p];
#pragma unroll
  for (int j = 0; j < 4; ++j) {
    int gcol = g0 + wx * 64 + j * 16 + l15;
    if (gcol < 1552) {
      float bC = biasC[gcol], wC = wlC[gcol];
#pragma unroll
      for (int i = 0; i < 4; ++i)
#pragma unroll
        for (int p = 0; p < 4; ++p) {
          int grow = m0 + wy * 64 + i * 16 + lq * 4 + p;
          xkb[(size_t)grow * 1552 + gcol] = f2bf(acc[i][j][p] + bC + vt[i][p] * wC);
        }
    }
  }
}

// ------------------------- PH2: per-step scan kernel v3 --------------------
// launch t: gates(t-1) for 8 b-rows (redundant over 25 g-tiles) + xout_t.
// grid (25 g-tiles of 64, 32 b-tiles of 8), 256 threads.
// Wr transposed (WrT[384][1600]) -> lane g-index is fast axis (coalesced).
__global__ __launch_bounds__(256) void k_step(
    const u16* __restrict__ xkb, const float* __restrict__ wrT,
    const float* __restrict__ xoutA, float* __restrict__ xoutB,
    const float* __restrict__ cIn, float* __restrict__ cOut,
    float* __restrict__ hbuf, float* __restrict__ dbuf, int t) {
  __shared__ alignas(16) float Hs[8][384];  // h(t-1) rows, broadcast reads
  __shared__ float fmS[8][8], imS[8][8];
  int tid = threadIdx.x;
  int g0 = blockIdx.x * 64, b0 = blockIdx.y * 8;

  if (t > 0) {
    if (tid < 8) {
      int b = b0 + tid;
      const float* xr = xoutA + (size_t)b * 1552;
      float z[8], e[8], m, s, inv, run, fsum;
      m = -1e30f;
      for (int j = 0; j < 8; ++j) { z[j] = xr[j]; m = fmaxf(m, z[j]); }
      s = 0.f;
      for (int j = 0; j < 8; ++j) { e[j] = __expf(z[j] - m); s += e[j]; }
      inv = 1.f / s; run = 0.f; fsum = 0.f;
      for (int j = 0; j < 8; ++j) { run += e[j] * inv; fmS[tid][j] = run; fsum += run; }
      dbuf[(size_t)(t - 1) * 256 + b] = 1.f - fsum * 0.125f;
      m = -1e30f;
      for (int j = 0; j < 8; ++j) { z[j] = xr[8 + j]; m = fmaxf(m, z[j]); }
      s = 0.f;
      for (int j = 0; j < 8; ++j) { e[j] = __expf(z[j] - m); s += e[j]; }
      inv = 1.f / s; run = 0.f;
      for (int j = 7; j >= 0; --j) { run += e[j] * inv; imS[tid][j] = run; }
    }
    __syncthreads();
#pragma unroll
    for (int rep = 0; rep < 12; ++rep) {
      int eidx = rep * 256 + tid;  // 0..3071
      int bl = eidx / 384;
      int h = eidx - bl * 384;
      int l = h / 48;
      int b = b0 + bl;
      const float* xg = xoutA + (size_t)b * 1552 + 16;
      float fg = sigf(xg[h]);
      float ig = sigf(xg[h + 384]);
      float og = sigf(xg[h + 768]);
      float ci = tanhf_(xg[h + 1152]);
      float cl = cIn[b * 384 + h];
      float fm = fmS[bl][l], im = imS[bl][l];
      float ov = fm * im;
      float cn = ov * (fg * cl + ig * ci) + (fm - ov) * cl + (im - ov) * ci;
      float hn = og * tanhf_(cn);
      cOut[b * 384 + h] = cn;
      hbuf[((size_t)(t - 1) * 256 + b) * 384 + h] = hn;
      Hs[bl][h] = hn;
    }
  } else {
    for (int i = tid; i < 8 * 384; i += 256) ((float*)Hs)[i] = 0.f;
  }
  __syncthreads();

  // xout_t[b][g] = XK[b,t,g] + sum_k h[b][k] * WrT[k][g]
  int gl = tid & 63;   // lanes 0..63 -> consecutive g (coalesced 256B loads)
  int bp = tid >> 6;   // 0..3 -> rows {bp, bp+4}
  int g = g0 + gl;
  float acc0 = 0.f, acc1 = 0.f;
  if (t > 0) {
    const float* wcol = wrT + g;
    const float* h0 = Hs[bp];
    const float* h1 = Hs[bp + 4];
    for (int k = 0; k < 384; k += 8) {
#pragma unroll
      for (int u = 0; u < 8; ++u) {
        float wv = wcol[(size_t)(k + u) * 1600];
        acc0 += h0[k + u] * wv;
        acc1 += h1[k + u] * wv;
      }
    }
  }
  if (g < 1552) {
    int bA = b0 + bp, bB = b0 + bp + 4;
    xoutB[(size_t)bA * 1552 + g] =
        acc0 + bf2f(xkb[((size_t)bA * 50 + t) * 1552 + g]);
    xoutB[(size_t)bB * 1552 + g] =
        acc1 + bf2f(xkb[((size_t)bB * 50 + t) * 1552 + g]);
  }
}

// ------------------------- PH3: final (gates49 + theme/conv/out) -----------
__global__ __launch_bounds__(384) void k_final(
    const float* __restrict__ xout49, const float* __restrict__ c48,
    const float* __restrict__ hbuf, const float* __restrict__ dbuf,
    const unsigned char* __restrict__ am, const float* __restrict__ smalls,
    const u16* __restrict__ wcp, float* __restrict__ out) {
  const float* WsF = smalls + 12800;
  const float* bsF = smalls + 37376;
  const float* WrsF = smalls + 37440;
  const float* brsF = smalls + 62016;
  const float* bcF = smalls + 62400;
  const float* WoF = smalls + 62784;
  const float* boF = smalls + 111936;
  __shared__ alignas(16) float Hl[384];
  __shared__ alignas(16) float lh2[10][384];
  __shared__ alignas(16) float ti[384];
  __shared__ alignas(16) float us[64];
  __shared__ alignas(16) float rnnS[384];
  __shared__ alignas(16) float hlastS[384];
  __shared__ float fm8[8], im8[8], ldS[10];
  __shared__ float d49S;
  __shared__ int npad[50];
  __shared__ int lastS;
  int tid = threadIdx.x;
  int b = blockIdx.x;

  if (tid < 50) {
    const unsigned char* mr = am + ((size_t)b * 50 + tid) * 64;
    int all1 = 1;
    for (int q = 0; q < 64; ++q) all1 &= (mr[q] != 0);
    npad[tid] = all1 ? 0 : 1;
  }
  if (tid == 0) {
    const float* xr = xout49 + (size_t)b * 1552;
    float z[8], e[8], m, s, inv, run, fsum;
    m = -1e30f;
    for (int j = 0; j < 8; ++j) { z[j] = xr[j]; m = fmaxf(m, z[j]); }
    s = 0.f;
    for (int j = 0; j < 8; ++j) { e[j] = __expf(z[j] - m); s += e[j]; }
    inv = 1.f / s; run = 0.f; fsum = 0.f;
    for (int j = 0; j < 8; ++j) { run += e[j] * inv; fm8[j] = run; fsum += run; }
    d49S = 1.f - fsum * 0.125f;
    m = -1e30f;
    for (int j = 0; j < 8; ++j) { z[j] = xr[8 + j]; m = fmaxf(m, z[j]); }
    s = 0.f;
    for (int j = 0; j < 8; ++j) { e[j] = __expf(z[j] - m); s += e[j]; }
    inv = 1.f / s; run = 0.f;
    for (int j = 7; j >= 0; --j) { run += e[j] * inv; im8[j] = run; }
  }
  __syncthreads();
  {  // gates for step 49 -> h49
    int h = tid;
    const float* xg = xout49 + (size_t)b * 1552 + 16;
    int l = h / 48;
    float fg = sigf(xg[h]);
    float ig = sigf(xg[h + 384]);
    float og = sigf(xg[h + 768]);
    float ci = tanhf_(xg[h + 1152]);
    float cl = c48[b * 384 + h];
    float fm = fm8[l], im = im8[l];
    float ov = fm * im;
    float cn = ov * (fg * cl + ig * ci) + (fm - ov) * cl + (im - ov) * ci;
    Hl[h] = og * tanhf_(cn);
  }
  if (tid == 0) {
    int c = 0;
    for (int v = 0; v < 50; ++v) c += npad[v];
    int lv = c - 1;
    lastS = lv < 0 ? 0 : lv;
  }
  __syncthreads();
  if (tid == 0) {  // window cumsum + softmax -> local_dis
    float cum = 0.f, cv[10];
    for (int k = 0; k < 10; ++k) {
      int s = lastS - 9 + k;
      float dk = 0.f;
      if (s >= 0) dk = (s == 49) ? d49S : dbuf[(size_t)s * 256 + b];
      cum += dk;
      cv[k] = cum;
    }
    float m = cv[0];
    for (int k = 1; k < 10; ++k) m = fmaxf(m, cv[k]);
    float ssum = 0.f, ee[10];
    for (int k = 0; k < 10; ++k) { ee[k] = __expf(cv[k] - m); ssum += ee[k]; }
    float inv = 1.f / ssum;
    for (int k = 0; k < 10; ++k) ldS[k] = ee[k] * inv;
  }
  __syncthreads();
  {  // local_h, theme input, h_last
    int h = tid;
    float ssum = 0.f;
    for (int k = 0; k < 10; ++k) {
      int s = lastS - 9 + k;
      float hv = 0.f;
      if (s >= 0)
        hv = (s == 49) ? Hl[h] : hbuf[((size_t)s * 256 + b) * 384 + h];
      float v = hv * ldS[k];
      lh2[k][h] = v;
      ssum += v;
    }
    ti[h] = ssum * 0.1f;
    hlastS[h] = (lastS == 49) ? Hl[h] : hbuf[((size_t)lastS * 256 + b) * 384 + h];
  }
  __syncthreads();
  if (tid < 64) {  // u = relu(ti @ Ws^T + bs)
    float a = bsF[tid];
    const float* wr = WsF + (size_t)tid * 384;
    for (int h = 0; h < 384; ++h) a += wr[h] * ti[h];
    us[tid] = fmaxf(a, 0.f);
  }
  __syncthreads();
  {  // theme = sigmoid(u @ Wrs^T + brs); conv; rnn = theme*conv + h_last
    int o = tid;
    float th = brsF[o];
    const float* wr = WrsF + (size_t)o * 64;
    for (int k = 0; k < 64; ++k) th += wr[k] * us[k];
    th = sigf(th);
    float cacc = bcF[o];
    for (int k = 0; k < 10; ++k) {
      const u16* wrow = wcp + ((size_t)o * 10 + k) * 384;
      const float* lrow = lh2[k];
      for (int h8 = 0; h8 < 48; ++h8) cacc += dot8_bf(wrow + h8 * 8, lrow + h8 * 8);
    }
    rnnS[o] = th * cacc + hlastS[o];
  }
  __syncthreads();
  if (tid < 128) {  // out = rnn @ Wo^T + bo, fp32
    float a = boF[tid];
    const float* wr = WoF + (size_t)tid * 384;
    for (int h = 0; h < 384; ++h) a += wr[h] * rnnS[h];
    out[(size_t)b * 128 + tid] = a;
  }
}

// ------------------------- launch ------------------------------------------
extern "C" void kernel_launch(void* const* d_in, const int* in_sizes, int n_in,
                              void* d_out, int out_size, void* d_ws, size_t ws_size,
                              hipStream_t stream) {
  const int* node_ids = (const int*)d_in[0];
  const void* vtR = d_in[3];
  const unsigned char* am = (const unsigned char*)d_in[5];
  const void* embR = d_in[6];
  const void* WkR = d_in[7];
  const void* bkR = d_in[8];
  const void* WrR = d_in[9];
  const void* brR = d_in[10];
  const void* WsR = d_in[11];
  const void* bsR = d_in[12];
  const void* WrsR = d_in[13];
  const void* brsR = d_in[14];
  const void* WcR = d_in[15];
  const void* bcR = d_in[16];
  const void* WoR = d_in[17];
  const void* boR = d_in[18];
  (void)in_sizes; (void)n_in; (void)out_size; (void)ws_size;

  char* ws = (char*)d_ws;
  size_t off = 0;
  auto alloc = [&](size_t bytes) {
    void* p = ws + off;
    off = (off + bytes + 255) & ~(size_t)255;
    return p;
  };
  int* flagp = (int*)alloc(4);
  u16* embB = (u16*)alloc((size_t)10001 * 128 * 2);      // 2.56MB
  u16* WkP = (u16*)alloc((size_t)1664 * 8192 * 2);       // 27.3MB
  float* WrT = (float*)alloc((size_t)384 * 1600 * 4);    // 2.46MB transposed
  float* biasC = (float*)alloc(1552 * 4);
  float* wlC = (float*)alloc(1552 * 4);
  float* smalls = (float*)alloc((size_t)112064 * 4);
  u16* XKb = (u16*)alloc((size_t)12800 * 1552 * 2);      // 39.7MB
  u16* WcP = (u16*)alloc((size_t)384 * 3840 * 2);        // 2.9MB
  float* xout = (float*)alloc((size_t)2 * 256 * 1552 * 4);  // 3.2MB
  float* Cbuf = (float*)alloc((size_t)2 * 256 * 384 * 4);   // 0.8MB
  float* Hbuf = (float*)alloc((size_t)50 * 256 * 384 * 4);  // 19.7MB
  float* Dbuf = (float*)alloc((size_t)50 * 256 * 4);

  k_detect<<<dim3(1), dim3(64), 0, stream>>>((const unsigned int*)embR, flagp);
  k_cvt_emb<<<dim3(1024), dim3(256), 0, stream>>>(embR, embB, flagp);
  k_repack_wk<<<dim3(2048), dim3(256), 0, stream>>>(WkR, WkP, flagp);
  k_prep_wr<<<dim3(512), dim3(256), 0, stream>>>(WrR, WkR, bkR, brR, WrT, biasC,
                                                 wlC, flagp);
  k_repack_wc<<<dim3(512), dim3(256), 0, stream>>>(WcR, WcP, flagp);
  k_cvt_smalls<<<dim3(128), dim3(256), 0, stream>>>(vtR, WsR, bsR, WrsR, brsR,
                                                    bcR, WoR, boR, smalls, flagp);
  k_zero<<<dim3(96), dim3(256), 0, stream>>>(Cbuf, 256 * 384);  // c_{-1}=0

  k_gemm_xk<<<dim3(13, 100), dim3(256), 0, stream>>>(node_ids, embB, WkP, smalls,
                                                     biasC, wlC, XKb);

  for (int t = 0; t < 50; ++t) {
    const float* xA = xout + (size_t)((t + 1) & 1) * (256 * 1552);
    float* xB = xout + (size_t)(t & 1) * (256 * 1552);
    const float* cI = Cbuf + (size_t)((t + 1) & 1) * (256 * 384);
    float* cO = Cbuf + (size_t)(t & 1) * (256 * 384);
    k_step<<<dim3(25, 32), dim3(256), 0, stream>>>(XKb, WrT, xA, xB, cI, cO,
                                                   Hbuf, Dbuf, t);
  }

  k_final<<<dim3(256), dim3(384), 0, stream>>>(
      xout + (size_t)1 * (256 * 1552), Cbuf + (size_t)1 * (256 * 384), Hbuf, Dbuf,
      am, smalls, WcP, (float*)d_out);
}

// Round 11
// 1713.679 us; speedup vs baseline: 2.6869x; 1.3292x over previous
//
#include <hip/hip_runtime.h>
#include <stdint.h>

// ---------------------------------------------------------------------------
// StageNet forward on MI355X — ROUND 11.
// R10: 2278us. k_step ~30us/step (25x redundant same-address global writes +
// scalar GEMM), k_gemm_xk 620us (read-side LDS conflicts: 128B row stride =
// 32-bank alias on ds_read_b128).
// This round:
//  * k_gemm_xk v3: XOR-swizzled staging (global chunk lc^lr -> store chunk lc;
//    read chunk (ks*4+lq)^(l15&7)) — conflict-free b128 reads, GLL kept.
//  * k_step v5: MFMA 16x16x32 bf16 for h@Wr^T (h,Wr bf16; fp32 acc), grid
//    (25 g-tiles x 16 b-tiles), gates computed redundantly but cOut/hbuf/dbuf
//    written only by blockIdx.x==0 (kills cross-XCD same-line write storm).
// Pipeline: detect -> canonicalize -> PH1 MFMA gather-GEMM XKb(bf16) ->
// 50x k_step -> k_final (fp32 out).
// ---------------------------------------------------------------------------

typedef unsigned short u16;
typedef short bf16x8 __attribute__((ext_vector_type(8)));
typedef float f32x4 __attribute__((ext_vector_type(4)));

#define GLL(gp, lp)                                                            \
  __builtin_amdgcn_global_load_lds(                                            \
      (const __attribute__((address_space(1))) unsigned int*)(gp),             \
      (__attribute__((address_space(3))) unsigned int*)(lp), 16, 0, 0)

__device__ __forceinline__ float bf2f(u16 u) {
  union { unsigned int i; float f; } v;
  v.i = ((unsigned int)u) << 16;
  return v.f;
}
__device__ __forceinline__ u16 f2bf(float f) {
  union { float f; unsigned int i; } v;
  v.f = f;
  unsigned int r = (v.i + 0x7fffu + ((v.i >> 16) & 1u)) >> 16;
  return (u16)r;
}
__device__ __forceinline__ float ldf(const void* p, size_t i, int isbf) {
  return isbf ? bf2f(((const u16*)p)[i]) : ((const float*)p)[i];
}
__device__ __forceinline__ float sigf(float x) { return 1.f / (1.f + __expf(-x)); }
__device__ __forceinline__ float tanhf_(float x) {
  float cx = fminf(fmaxf(x, -15.f), 15.f);
  float e = __expf(2.f * cx);
  return (e - 1.f) / (e + 1.f);
}
__device__ __forceinline__ float dot8_bf(const u16* w, const float* lp) {
  uint4 wv = *(const uint4*)w;
  union { unsigned int u; float f; } a0, a1;
  float s;
  a0.u = wv.x << 16; a1.u = wv.x & 0xffff0000u;
  s = lp[0] * a0.f + lp[1] * a1.f;
  a0.u = wv.y << 16; a1.u = wv.y & 0xffff0000u;
  s += lp[2] * a0.f + lp[3] * a1.f;
  a0.u = wv.z << 16; a1.u = wv.z & 0xffff0000u;
  s += lp[4] * a0.f + lp[5] * a1.f;
  a0.u = wv.w << 16; a1.u = wv.w & 0xffff0000u;
  s += lp[6] * a0.f + lp[7] * a1.f;
  return s;
}

// ------------------------- dtype detection (safety) ------------------------
__global__ void k_detect(const unsigned int* __restrict__ emb_raw,
                         int* __restrict__ flag) {
  if (blockIdx.x == 0 && threadIdx.x == 0) {
    int cnt = 0;
    for (int i = 64; i < 128; ++i) {
      unsigned int u = emb_raw[i];
      unsigned int lo = u & 0xffffu;
      unsigned int ex = (lo >> 7) & 0xffu;
      if (lo != 0 && ex >= 100 && ex <= 126) ++cnt;
    }
    *flag = (cnt >= 32) ? 1 : 0;
  }
}

// ------------------------- canonicalization --------------------------------
__global__ void k_cvt_emb(const void* __restrict__ src, u16* __restrict__ dst,
                          const int* __restrict__ flagp) {
  int isbf = *flagp;
  int n = 10001 * 128;
  int i = blockIdx.x * blockDim.x + threadIdx.x;
  int stride = gridDim.x * blockDim.x;
  for (; i < n; i += stride)
    dst[i] = isbf ? ((const u16*)src)[i] : f2bf(((const float*)src)[i]);
}

__global__ void k_repack_wk(const void* __restrict__ wk, u16* __restrict__ wkp,
                            const int* __restrict__ flagp) {
  int isbf = *flagp;
  size_t i = (size_t)blockIdx.x * blockDim.x + threadIdx.x;
  size_t total = (size_t)1664 * 8192;
  size_t stride = (size_t)gridDim.x * blockDim.x;
  for (; i < total; i += stride) {
    size_t g = i >> 13, k = i & 8191;
    wkp[i] = (g < 1552) ? f2bf(ldf(wk, g * 8193 + k, isbf)) : (u16)0;
  }
}

// wrBf[g][k] bf16, g padded to 1600 (zeros); + biasC, wlC
__global__ void k_prep_wr(const void* __restrict__ wr, const void* __restrict__ wk,
                          const void* __restrict__ bk, const void* __restrict__ br,
                          u16* __restrict__ wrBf, float* __restrict__ biasC,
                          float* __restrict__ wlC, const int* __restrict__ flagp) {
  int isbf = *flagp;
  int i0 = blockIdx.x * blockDim.x + threadIdx.x;
  int stride = gridDim.x * blockDim.x;
  for (int j = i0; j < 1600 * 384; j += stride) {
    int g = j / 384, k = j - g * 384;
    wrBf[j] = (g < 1552) ? f2bf(ldf(wr, (size_t)g * 385 + k, isbf)) : (u16)0;
  }
  for (int g = i0; g < 1552; g += stride) {
    biasC[g] = ldf(bk, g, isbf) + ldf(br, g, isbf);
    wlC[g] = ldf(wk, (size_t)g * 8193 + 8192, isbf) + ldf(wr, g * 385 + 384, isbf);
  }
}

__global__ void k_repack_wc(const void* __restrict__ wc, u16* __restrict__ wcp,
                            const int* __restrict__ flagp) {
  int isbf = *flagp;
  int i0 = blockIdx.x * blockDim.x + threadIdx.x;
  int stride = gridDim.x * blockDim.x;
  for (int j = i0; j < 384 * 3840; j += stride) {
    int o = j / 3840;
    int r = j - o * 3840;
    int k = r / 384;
    int h = r - k * 384;
    wcp[j] = f2bf(ldf(wc, (o * 384 + h) * 10 + k, isbf));  // [o][h][k]->[o][k][h]
  }
}

// canonical fp32: [vt 12800][Ws 24576][bs 64][Wrs 24576][brs 384][bc 384]
//                 [Wo 49152][bo 128]  (total 112064 floats)
__global__ void k_cvt_smalls(const void* vt, const void* Ws, const void* bs,
                             const void* Wrs, const void* brs, const void* bc,
                             const void* Wo, const void* bo,
                             float* __restrict__ dst, const int* __restrict__ flagp) {
  int isbf = *flagp;
  int i = blockIdx.x * blockDim.x + threadIdx.x;
  int stride = gridDim.x * blockDim.x;
  for (; i < 112064; i += stride) {
    float v;
    if (i < 12800) v = ldf(vt, i, isbf);
    else if (i < 37376) v = ldf(Ws, i - 12800, isbf);
    else if (i < 37440) v = ldf(bs, i - 37376, isbf);
    else if (i < 62016) v = ldf(Wrs, i - 37440, isbf);
    else if (i < 62400) v = ldf(brs, i - 62016, isbf);
    else if (i < 62784) v = ldf(bc, i - 62400, isbf);
    else if (i < 111936) v = ldf(Wo, i - 62784, isbf);
    else v = ldf(bo, i - 111936, isbf);
    dst[i] = v;
  }
}

__global__ void k_zero(float* __restrict__ p, int n) {
  int i = blockIdx.x * blockDim.x + threadIdx.x;
  int stride = gridDim.x * blockDim.x;
  for (; i < n; i += stride) p[i] = 0.f;
}

// ------------------------- PH1: gathered GEMM, swizzled GLL staging --------
// grid (13 g-tiles, 100 m-tiles), 256 threads. Tile 128x128, BK=64 bf16.
// XOR swizzle: LDS chunk j of row r holds global 16B-chunk j^(r&7); reads
// become conflict-free (8 lanes per 4-bank group = the b128 minimum).
__global__ __launch_bounds__(256) void k_gemm_xk(
    const int* __restrict__ node_ids, const u16* __restrict__ embB,
    const u16* __restrict__ wkp, const float* __restrict__ vtF,
    const float* __restrict__ biasC, const float* __restrict__ wlC,
    u16* __restrict__ xkb) {
  __shared__ alignas(16) u16 As[128 * 64];
  __shared__ alignas(16) u16 Bs[128 * 64];
  int tid = threadIdx.x;
  int m0 = blockIdx.y * 128;
  int g0 = blockIdx.x * 128;
  int lane = tid & 63, w = tid >> 6;
  int wy = w >> 1, wx = w & 1;
  f32x4 acc[4][4];
#pragma unroll
  for (int i = 0; i < 4; ++i)
#pragma unroll
    for (int j = 0; j < 4; ++j) acc[i][j] = (f32x4){0.f, 0.f, 0.f, 0.f};

  int l15 = lane & 15, lq = lane >> 4;
  int lr = lane >> 3, lc = lane & 7;  // row-in-chunk, 16B-chunk slot
  int swc = (lc ^ lr) * 8;            // swizzled global chunk offset (u16)
  int cRd = (lq ^ (l15 & 7)) * 8;     // swizzled read chunk, ks=0 (u16)

  for (int kt = 0; kt < 128; ++kt) {
    __syncthreads();
    // ---- stage A (gathered embed rows), swizzled global chunk
#pragma unroll
    for (int c = 0; c < 4; ++c) {
      int chunk = w * 4 + c;
      int r = chunk * 8 + lr;
      int id = node_ids[(size_t)(m0 + r) * 64 + (kt >> 1)];
      const u16* gp = embB + (size_t)id * 128 + (kt & 1) * 64 + swc;
      u16* lp = As + chunk * 512 + lane * 8;
      GLL(gp, lp);
    }
    // ---- stage B (Wk tile), swizzled global chunk
#pragma unroll
    for (int c = 0; c < 4; ++c) {
      int chunk = w * 4 + c;
      int r = chunk * 8 + lr;
      const u16* gp = wkp + (size_t)(g0 + r) * 8192 + (size_t)kt * 64 + swc;
      u16* lp = Bs + chunk * 512 + lane * 8;
      GLL(gp, lp);
    }
    __syncthreads();
    const u16* Ab = As + (wy * 64 + l15) * 64;
    const u16* Bb = Bs + (wx * 64 + l15) * 64;
#pragma unroll
    for (int ks = 0; ks < 2; ++ks) {
      int co = cRd ^ (ks * 32);
      bf16x8 av[4], bv[4];
#pragma unroll
      for (int i = 0; i < 4; ++i) av[i] = *(const bf16x8*)(Ab + i * 1024 + co);
#pragma unroll
      for (int j = 0; j < 4; ++j) bv[j] = *(const bf16x8*)(Bb + j * 1024 + co);
#pragma unroll
      for (int i = 0; i < 4; ++i)
#pragma unroll
        for (int j = 0; j < 4; ++j)
          acc[i][j] =
              __builtin_amdgcn_mfma_f32_16x16x32_bf16(av[i], bv[j], acc[i][j], 0, 0, 0);
    }
  }
  float vt[4][4];
#pragma unroll
  for (int i = 0; i < 4; ++i)
#pragma unroll
    for (int p = 0; p < 4; ++p)
      vt[i][p] = vtF[m0 + wy * 64 + i * 16 + lq * 4 + p];
#pragma unroll
  for (int j = 0; j < 4; ++j) {
    int gcol = g0 + wx * 64 + j * 16 + l15;
    if (gcol < 1552) {
      float bC = biasC[gcol], wC = wlC[gcol];
#pragma unroll
      for (int i = 0; i < 4; ++i)
#pragma unroll
        for (int p = 0; p < 4; ++p) {
          int grow = m0 + wy * 64 + i * 16 + lq * 4 + p;
          xkb[(size_t)grow * 1552 + gcol] = f2bf(acc[i][j][p] + bC + vt[i][p] * wC);
        }
    }
  }
}

// ------------------------- PH2: per-step scan kernel v5 (MFMA) -------------
// launch t: gates(t-1) for 16 b-rows (redundant per g-tile; single-writer
// globals) + xout_t = XK_t + h@Wr^T via MFMA 16x16x32 bf16.
// grid (25 g-tiles of 64, 16 b-tiles of 16), 256 threads = 4 waves; wave wx
// covers g-range [g0+wx*16, +16).
__global__ __launch_bounds__(256) void k_step(
    const u16* __restrict__ xkb, const u16* __restrict__ wrBf,
    const float* __restrict__ xoutA, float* __restrict__ xoutB,
    const float* __restrict__ cIn, float* __restrict__ cOut,
    float* __restrict__ hbuf, float* __restrict__ dbuf, int t) {
  __shared__ alignas(16) u16 HsB[16][384];  // h_{t-1} bf16 (MFMA A operand)
  __shared__ float fmS[16][8], imS[16][8];
  int tid = threadIdx.x;
  int g0 = blockIdx.x * 64, b0 = blockIdx.y * 16;
  int wxv = tid >> 6, lane = tid & 63, l15 = lane & 15, lq = lane >> 4;
  bool writer = (blockIdx.x == 0);

  if (t > 0) {
    if (tid < 16) {
      int b = b0 + tid;
      const float* xr = xoutA + (size_t)b * 1552;
      float z[8], e[8], m, s, inv, run, fsum;
      m = -1e30f;
      for (int j = 0; j < 8; ++j) { z[j] = xr[j]; m = fmaxf(m, z[j]); }
      s = 0.f;
      for (int j = 0; j < 8; ++j) { e[j] = __expf(z[j] - m); s += e[j]; }
      inv = 1.f / s; run = 0.f; fsum = 0.f;
      for (int j = 0; j < 8; ++j) { run += e[j] * inv; fmS[tid][j] = run; fsum += run; }
      if (writer) dbuf[(size_t)(t - 1) * 256 + b] = 1.f - fsum * 0.125f;
      m = -1e30f;
      for (int j = 0; j < 8; ++j) { z[j] = xr[8 + j]; m = fmaxf(m, z[j]); }
      s = 0.f;
      for (int j = 0; j < 8; ++j) { e[j] = __expf(z[j] - m); s += e[j]; }
      inv = 1.f / s; run = 0.f;
      for (int j = 7; j >= 0; --j) { run += e[j] * inv; imS[tid][j] = run; }
    }
    __syncthreads();
#pragma unroll
    for (int rep = 0; rep < 24; ++rep) {
      int eidx = rep * 256 + tid;  // 0..6143
      int bl = eidx / 384;
      int h = eidx - bl * 384;
      int l = h / 48;
      int b = b0 + bl;
      const float* xg = xoutA + (size_t)b * 1552 + 16;
      float fg = sigf(xg[h]);
      float ig = sigf(xg[h + 384]);
      float og = sigf(xg[h + 768]);
      float ci = tanhf_(xg[h + 1152]);
      float cl = cIn[b * 384 + h];
      float fm = fmS[bl][l], im = imS[bl][l];
      float ov = fm * im;
      float cn = ov * (fg * cl + ig * ci) + (fm - ov) * cl + (im - ov) * ci;
      float hn = og * tanhf_(cn);
      if (writer) {
        cOut[b * 384 + h] = cn;
        hbuf[((size_t)(t - 1) * 256 + b) * 384 + h] = hn;
      }
      HsB[bl][h] = f2bf(hn);
    }
  } else {
    for (int i = tid; i < 16 * 384; i += 256) ((u16*)HsB)[i] = 0;
  }
  __syncthreads();

  // xout_t[b][g] = XK[b,t,g] + (h @ Wr^T)[b][g] via MFMA
  // A: HsB[m=l15][k]; B: wrBf[g=gRow][k]; D: b=b0+lq*4+p, g=gRow(l15 col)
  int gRow = g0 + wxv * 16 + l15;
  const u16* brow = wrBf + (size_t)gRow * 384;
  const u16* arow = &HsB[l15][0];
  f32x4 acc = (f32x4){0.f, 0.f, 0.f, 0.f};
#pragma unroll
  for (int ks = 0; ks < 12; ++ks) {
    bf16x8 af = *(const bf16x8*)(arow + ks * 32 + lq * 8);
    bf16x8 bfv = *(const bf16x8*)(brow + ks * 32 + lq * 8);
    acc = __builtin_amdgcn_mfma_f32_16x16x32_bf16(af, bfv, acc, 0, 0, 0);
  }
  if (gRow < 1552) {
#pragma unroll
    for (int p = 0; p < 4; ++p) {
      int b = b0 + lq * 4 + p;
      xoutB[(size_t)b * 1552 + gRow] =
          acc[p] + bf2f(xkb[((size_t)b * 50 + t) * 1552 + gRow]);
    }
  }
}

// ------------------------- PH3: final (gates49 + theme/conv/out) -----------
__global__ __launch_bounds__(384) void k_final(
    const float* __restrict__ xout49, const float* __restrict__ c48,
    const float* __restrict__ hbuf, const float* __restrict__ dbuf,
    const unsigned char* __restrict__ am, const float* __restrict__ smalls,
    const u16* __restrict__ wcp, float* __restrict__ out) {
  const float* WsF = smalls + 12800;
  const float* bsF = smalls + 37376;
  const float* WrsF = smalls + 37440;
  const float* brsF = smalls + 62016;
  const float* bcF = smalls + 62400;
  const float* WoF = smalls + 62784;
  const float* boF = smalls + 111936;
  __shared__ alignas(16) float Hl[384];
  __shared__ alignas(16) float lh2[10][384];
  __shared__ alignas(16) float ti[384];
  __shared__ alignas(16) float us[64];
  __shared__ alignas(16) float rnnS[384];
  __shared__ alignas(16) float hlastS[384];
  __shared__ float fm8[8], im8[8], ldS[10];
  __shared__ float d49S;
  __shared__ int npad[50];
  __shared__ int lastS;
  int tid = threadIdx.x;
  int b = blockIdx.x;

  if (tid < 50) {
    const unsigned char* mr = am + ((size_t)b * 50 + tid) * 64;
    int all1 = 1;
    for (int q = 0; q < 64; ++q) all1 &= (mr[q] != 0);
    npad[tid] = all1 ? 0 : 1;
  }
  if (tid == 0) {
    const float* xr = xout49 + (size_t)b * 1552;
    float z[8], e[8], m, s, inv, run, fsum;
    m = -1e30f;
    for (int j = 0; j < 8; ++j) { z[j] = xr[j]; m = fmaxf(m, z[j]); }
    s = 0.f;
    for (int j = 0; j < 8; ++j) { e[j] = __expf(z[j] - m); s += e[j]; }
    inv = 1.f / s; run = 0.f; fsum = 0.f;
    for (int j = 0; j < 8; ++j) { run += e[j] * inv; fm8[j] = run; fsum += run; }
    d49S = 1.f - fsum * 0.125f;
    m = -1e30f;
    for (int j = 0; j < 8; ++j) { z[j] = xr[8 + j]; m = fmaxf(m, z[j]); }
    s = 0.f;
    for (int j = 0; j < 8; ++j) { e[j] = __expf(z[j] - m); s += e[j]; }
    inv = 1.f / s; run = 0.f;
    for (int j = 7; j >= 0; --j) { run += e[j] * inv; im8[j] = run; }
  }
  __syncthreads();
  {  // gates for step 49 -> h49
    int h = tid;
    const float* xg = xout49 + (size_t)b * 1552 + 16;
    int l = h / 48;
    float fg = sigf(xg[h]);
    float ig = sigf(xg[h + 384]);
    float og = sigf(xg[h + 768]);
    float ci = tanhf_(xg[h + 1152]);
    float cl = c48[b * 384 + h];
    float fm = fm8[l], im = im8[l];
    float ov = fm * im;
    float cn = ov * (fg * cl + ig * ci) + (fm - ov) * cl + (im - ov) * ci;
    Hl[h] = og * tanhf_(cn);
  }
  if (tid == 0) {
    int c = 0;
    for (int v = 0; v < 50; ++v) c += npad[v];
    int lv = c - 1;
    lastS = lv < 0 ? 0 : lv;
  }
  __syncthreads();
  if (tid == 0) {  // window cumsum + softmax -> local_dis
    float cum = 0.f, cv[10];
    for (int k = 0; k < 10; ++k) {
      int s = lastS - 9 + k;
      float dk = 0.f;
      if (s >= 0) dk = (s == 49) ? d49S : dbuf[(size_t)s * 256 + b];
      cum += dk;
      cv[k] = cum;
    }
    float m = cv[0];
    for (int k = 1; k < 10; ++k) m = fmaxf(m, cv[k]);
    float ssum = 0.f, ee[10];
    for (int k = 0; k < 10; ++k) { ee[k] = __expf(cv[k] - m); ssum += ee[k]; }
    float inv = 1.f / ssum;
    for (int k = 0; k < 10; ++k) ldS[k] = ee[k] * inv;
  }
  __syncthreads();
  {  // local_h, theme input, h_last
    int h = tid;
    float ssum = 0.f;
    for (int k = 0; k < 10; ++k) {
      int s = lastS - 9 + k;
      float hv = 0.f;
      if (s >= 0)
        hv = (s == 49) ? Hl[h] : hbuf[((size_t)s * 256 + b) * 384 + h];
      float v = hv * ldS[k];
      lh2[k][h] = v;
      ssum += v;
    }
    ti[h] = ssum * 0.1f;
    hlastS[h] = (lastS == 49) ? Hl[h] : hbuf[((size_t)lastS * 256 + b) * 384 + h];
  }
  __syncthreads();
  if (tid < 64) {  // u = relu(ti @ Ws^T + bs)
    float a = bsF[tid];
    const float* wr = WsF + (size_t)tid * 384;
    for (int h = 0; h < 384; ++h) a += wr[h] * ti[h];
    us[tid] = fmaxf(a, 0.f);
  }
  __syncthreads();
  {  // theme = sigmoid(u @ Wrs^T + brs); conv; rnn = theme*conv + h_last
    int o = tid;
    float th = brsF[o];
    const float* wr = WrsF + (size_t)o * 64;
    for (int k = 0; k < 64; ++k) th += wr[k] * us[k];
    th = sigf(th);
    float cacc = bcF[o];
    for (int k = 0; k < 10; ++k) {
      const u16* wrow = wcp + ((size_t)o * 10 + k) * 384;
      const float* lrow = lh2[k];
      for (int h8 = 0; h8 < 48; ++h8) cacc += dot8_bf(wrow + h8 * 8, lrow + h8 * 8);
    }
    rnnS[o] = th * cacc + hlastS[o];
  }
  __syncthreads();
  if (tid < 128) {  // out = rnn @ Wo^T + bo, fp32
    float a = boF[tid];
    const float* wr = WoF + (size_t)tid * 384;
    for (int h = 0; h < 384; ++h) a += wr[h] * rnnS[h];
    out[(size_t)b * 128 + tid] = a;
  }
}

// ------------------------- launch ------------------------------------------
extern "C" void kernel_launch(void* const* d_in, const int* in_sizes, int n_in,
                              void* d_out, int out_size, void* d_ws, size_t ws_size,
                              hipStream_t stream) {
  const int* node_ids = (const int*)d_in[0];
  const void* vtR = d_in[3];
  const unsigned char* am = (const unsigned char*)d_in[5];
  const void* embR = d_in[6];
  const void* WkR = d_in[7];
  const void* bkR = d_in[8];
  const void* WrR = d_in[9];
  const void* brR = d_in[10];
  const void* WsR = d_in[11];
  const void* bsR = d_in[12];
  const void* WrsR = d_in[13];
  const void* brsR = d_in[14];
  const void* WcR = d_in[15];
  const void* bcR = d_in[16];
  const void* WoR = d_in[17];
  const void* boR = d_in[18];
  (void)in_sizes; (void)n_in; (void)out_size; (void)ws_size;

  char* ws = (char*)d_ws;
  size_t off = 0;
  auto alloc = [&](size_t bytes) {
    void* p = ws + off;
    off = (off + bytes + 255) & ~(size_t)255;
    return p;
  };
  int* flagp = (int*)alloc(4);
  u16* embB = (u16*)alloc((size_t)10001 * 128 * 2);      // 2.56MB
  u16* WkP = (u16*)alloc((size_t)1664 * 8192 * 2);       // 27.3MB
  u16* WrBf = (u16*)alloc((size_t)1600 * 384 * 2);       // 1.23MB bf16 [g][k]
  float* biasC = (float*)alloc(1552 * 4);
  float* wlC = (float*)alloc(1552 * 4);
  float* smalls = (float*)alloc((size_t)112064 * 4);
  u16* XKb = (u16*)alloc((size_t)12800 * 1552 * 2);      // 39.7MB
  u16* WcP = (u16*)alloc((size_t)384 * 3840 * 2);        // 2.9MB
  float* xout = (float*)alloc((size_t)2 * 256 * 1552 * 4);  // 3.2MB
  float* Cbuf = (float*)alloc((size_t)2 * 256 * 384 * 4);   // 0.8MB
  float* Hbuf = (float*)alloc((size_t)50 * 256 * 384 * 4);  // 19.7MB
  float* Dbuf = (float*)alloc((size_t)50 * 256 * 4);

  k_detect<<<dim3(1), dim3(64), 0, stream>>>((const unsigned int*)embR, flagp);
  k_cvt_emb<<<dim3(1024), dim3(256), 0, stream>>>(embR, embB, flagp);
  k_repack_wk<<<dim3(2048), dim3(256), 0, stream>>>(WkR, WkP, flagp);
  k_prep_wr<<<dim3(512), dim3(256), 0, stream>>>(WrR, WkR, bkR, brR, WrBf, biasC,
                                                 wlC, flagp);
  k_repack_wc<<<dim3(512), dim3(256), 0, stream>>>(WcR, WcP, flagp);
  k_cvt_smalls<<<dim3(128), dim3(256), 0, stream>>>(vtR, WsR, bsR, WrsR, brsR,
                                                    bcR, WoR, boR, smalls, flagp);
  k_zero<<<dim3(96), dim3(256), 0, stream>>>(Cbuf, 256 * 384);  // c_{-1}=0

  k_gemm_xk<<<dim3(13, 100), dim3(256), 0, stream>>>(node_ids, embB, WkP, smalls,
                                                     biasC, wlC, XKb);

  for (int t = 0; t < 50; ++t) {
    const float* xA = xout + (size_t)((t + 1) & 1) * (256 * 1552);
    float* xB = xout + (size_t)(t & 1) * (256 * 1552);
    const float* cI = Cbuf + (size_t)((t + 1) & 1) * (256 * 384);
    float* cO = Cbuf + (size_t)(t & 1) * (256 * 384);
    k_step<<<dim3(25, 16), dim3(256), 0, stream>>>(XKb, WrBf, xA, xB, cI, cO,
                                                   Hbuf, Dbuf, t);
  }

  k_final<<<dim3(256), dim3(384), 0, stream>>>(
      xout + (size_t)1 * (256 * 1552), Cbuf + (size_t)1 * (256 * 384), Hbuf, Dbuf,
      am, smalls, WcP, (float*)d_out);
}